// Round 2
// baseline (352.083 us; speedup 1.0000x reference)
//
#include <hip/hip_runtime.h>

typedef float  f32x4  __attribute__((ext_vector_type(4)));
typedef short  short8 __attribute__((ext_vector_type(8)));

#define BDIM 512
#define HID  256
#define BM   64
#define LPAD 264   // h LDS row stride in bf16 elems (256 + 8 pad)

__device__ __forceinline__ unsigned short f2bf(float f){
  union { float f; unsigned int u; } v; v.f = f;
  unsigned int u = v.u;
  return (unsigned short)((u + 0x7FFFu + ((u >> 16) & 1u)) >> 16);
}
__device__ __forceinline__ float bf2f(unsigned short h){
  union { unsigned int u; float f; } v; v.u = ((unsigned int)h) << 16;
  return v.f;
}

// ---------------- prep: pack W1[:, :4] and hi/lo bf16 fragment-ordered W2/W3 ----------------
// Fragment layout: flat idx f = ((n16*8 + ks)*64 + lane)*8 + j  holds
//   bf16( W[k][n] ) with k = ks*32 + (lane>>4)*8 + j, n = n16*16 + (lane&15)
__global__ __launch_bounds__(256) void prep_kernel(
    const float* __restrict__ W1, const float* __restrict__ W2,
    const float* __restrict__ W3, float* __restrict__ w1c,
    unsigned short* __restrict__ W2H, unsigned short* __restrict__ W2L,
    unsigned short* __restrict__ W3H, unsigned short* __restrict__ W3L)
{
  int t = blockIdx.x * 256 + threadIdx.x;
  if (t < 2048) {
    int k = t >> 2, j = t & 3;
    w1c[t] = W1[k * 256 + j];
  } else if (t < 2048 + 2 * 65536) {
    int f = t - 2048;
    const float* W = (f < 65536) ? W2 : W3;
    unsigned short* H = (f < 65536) ? W2H : W3H;
    unsigned short* L = (f < 65536) ? W2L : W3L;
    f &= 65535;
    int j = f & 7, lane = (f >> 3) & 63, ks = (f >> 9) & 7, n16 = f >> 12;
    int k = ks * 32 + (lane >> 4) * 8 + j;
    int n = n16 * 16 + (lane & 15);
    float wv = W[k * 256 + n];
    unsigned short hi = f2bf(wv);
    H[f] = hi;
    L[f] = f2bf(wv - bf2f(hi));
  }
}

// ---------------- MFMA tile: A hi/lo = [64][LPAD] bf16 LDS, B hi/lo = frag-ordered global ----
__device__ __forceinline__ void gemm_tile(
    const unsigned short* Ahi, const unsigned short* Alo,
    const unsigned short* __restrict__ BH, const unsigned short* __restrict__ BL,
    int w, int lane, f32x4 acc[4][4])
{
  const int l15 = lane & 15, l4 = lane >> 4;
  #pragma unroll
  for (int ks = 0; ks < 8; ks++) {
    short8 ah[4], al[4];
    #pragma unroll
    for (int m = 0; m < 4; m++) {
      ah[m] = *(const short8*)&Ahi[(m * 16 + l15) * LPAD + ks * 32 + l4 * 8];
      al[m] = *(const short8*)&Alo[(m * 16 + l15) * LPAD + ks * 32 + l4 * 8];
    }
    #pragma unroll
    for (int nf = 0; nf < 4; nf++) {
      int n16 = w * 4 + nf;
      size_t boff = (size_t)(((n16 * 8 + ks) * 64) + lane) * 8;
      short8 bh = *(const short8*)&BH[boff];
      short8 bl = *(const short8*)&BL[boff];
      #pragma unroll
      for (int m = 0; m < 4; m++) {
        acc[m][nf] = __builtin_amdgcn_mfma_f32_16x16x32_bf16(ah[m], bh, acc[m][nf], 0, 0, 0);
        acc[m][nf] = __builtin_amdgcn_mfma_f32_16x16x32_bf16(al[m], bh, acc[m][nf], 0, 0, 0);
        acc[m][nf] = __builtin_amdgcn_mfma_f32_16x16x32_bf16(ah[m], bl, acc[m][nf], 0, 0, 0);
      }
    }
  }
}

__global__ __launch_bounds__(256) void qmlp_kernel(
    const float* __restrict__ x,  const float* __restrict__ b1,
    const float* __restrict__ qp, const float* __restrict__ Wr,
    const float* __restrict__ br, const float* __restrict__ b2,
    const float* __restrict__ b3, const float* __restrict__ w1c,
    const unsigned short* __restrict__ W2H, const unsigned short* __restrict__ W2L,
    const unsigned short* __restrict__ W3H, const unsigned short* __restrict__ W3L,
    float* __restrict__ out)
{
  __shared__ float zlds[BM * 4];
  __shared__ unsigned short a_hi[BM * LPAD];   // holds h, then reused for h2
  __shared__ unsigned short a_lo[BM * LPAD];

  const int tid  = threadIdx.x;
  const int w    = tid >> 6, lane = tid & 63;
  const int row0 = blockIdx.x * BM;

  // ---- Phase A: angles = relu(x @ W1[:, :4] + b1[:4]); one row per wave-pass ----
  f32x4 wc[8];
  {
    const f32x4* w1c4 = (const f32x4*)w1c;   // [512] rows of 4 cols
    #pragma unroll
    for (int e = 0; e < 8; e++) wc[e] = w1c4[lane * 8 + e];
  }
  const f32x4 b1v = *(const f32x4*)b1;
  float a0 = 0.f, a1 = 0.f, a2 = 0.f, a3 = 0.f;
  #pragma unroll 2
  for (int rr = 0; rr < 16; rr++) {
    int grow = row0 + w * 16 + rr;
    const f32x4* xr = (const f32x4*)(x + (size_t)grow * BDIM) + lane * 2;
    f32x4 xa = xr[0], xb = xr[1];
    f32x4 p = xa[0] * wc[0];
    p += xa[1] * wc[1];  p += xa[2] * wc[2];  p += xa[3] * wc[3];
    p += xb[0] * wc[4];  p += xb[1] * wc[5];  p += xb[2] * wc[6];  p += xb[3] * wc[7];
    #pragma unroll
    for (int off = 32; off > 0; off >>= 1) {
      p[0] += __shfl_xor(p[0], off);
      p[1] += __shfl_xor(p[1], off);
      p[2] += __shfl_xor(p[2], off);
      p[3] += __shfl_xor(p[3], off);
    }
    if (lane == rr) {
      a0 = fmaxf(p[0] + b1v[0], 0.f);
      a1 = fmaxf(p[1] + b1v[1], 0.f);
      a2 = fmaxf(p[2] + b1v[2], 0.f);
      a3 = fmaxf(p[3] + b1v[3], 0.f);
    }
  }

  // ---- Phase B: per-sample 4-qubit statevector sim (lanes 0..15 of each wave) ----
  if (lane < 16) {
    float g00r[4], g00i[4], g01r[4], g01i[4], g10r[4], g10i[4], g11r[4], g11i[4];
    #pragma unroll
    for (int q = 0; q < 4; q++) {
      float phi = qp[q * 3 + 0], th = qp[q * 3 + 1], om = qp[q * 3 + 2];
      float c = cosf(0.5f * th), s = sinf(0.5f * th);
      float A1 = 0.5f * (phi + om), A2 = 0.5f * (phi - om);
      float c1 = cosf(A1), s1 = sinf(A1), c2 = cosf(A2), s2 = sinf(A2);
      g00r[q] =  c * c1;  g00i[q] = -c * s1;   // e^{-i(phi+om)/2} cos
      g01r[q] = -s * c2;  g01i[q] = -s * s2;   // -e^{+i(phi-om)/2} sin
      g10r[q] =  s * c2;  g10i[q] = -s * s2;   // e^{-i(phi-om)/2} sin
      g11r[q] =  c * c1;  g11i[q] =  c * s1;   // e^{+i(phi+om)/2} cos
    }
    float cr0 = cosf(0.5f * a0), sv0 = sinf(0.5f * a0);
    float cr1 = cosf(0.5f * a1), sv1 = sinf(0.5f * a1);
    float cr2 = cosf(0.5f * a2), sv2 = sinf(0.5f * a2);
    float cr3 = cosf(0.5f * a3), sv3 = sinf(0.5f * a3);
    float sr[16], si[16];
    #pragma unroll
    for (int i = 0; i < 16; i++) {       // product state after RY embedding (real)
      float v = ((i & 8) ? sv0 : cr0) * ((i & 4) ? sv1 : cr1) *
                ((i & 2) ? sv2 : cr2) * ((i & 1) ? sv3 : cr3);
      sr[i] = v; si[i] = 0.f;
    }
    #pragma unroll
    for (int q = 0; q < 4; q++) {        // Rot gates
      const int st = 8 >> q;
      #pragma unroll
      for (int i = 0; i < 16; i++) {
        if (i & st) continue;
        const int i1 = i + st;
        float xr_ = sr[i], xi_ = si[i], yr_ = sr[i1], yi_ = si[i1];
        sr[i]  = g00r[q] * xr_ - g00i[q] * xi_ + g01r[q] * yr_ - g01i[q] * yi_;
        si[i]  = g00r[q] * xi_ + g00i[q] * xr_ + g01r[q] * yi_ + g01i[q] * yr_;
        sr[i1] = g10r[q] * xr_ - g10i[q] * xi_ + g11r[q] * yr_ - g11i[q] * yi_;
        si[i1] = g10r[q] * xi_ + g10i[q] * xr_ + g11r[q] * yi_ + g11i[q] * yr_;
      }
    }
    #pragma unroll
    for (int q = 0; q < 3; q++) {        // adjacent CNOTs
      const int cb = 8 >> q, tb = 4 >> q;
      #pragma unroll
      for (int i = 0; i < 16; i++) {
        if ((i & cb) && !(i & tb)) {
          const int j = i | tb;
          float t1 = sr[i]; sr[i] = sr[j]; sr[j] = t1;
          float t2 = si[i]; si[i] = si[j]; si[j] = t2;
        }
      }
    }
    float z0 = 0.f, z1 = 0.f, z2 = 0.f, z3 = 0.f;
    #pragma unroll
    for (int i = 0; i < 16; i++) {
      float pb = sr[i] * sr[i] + si[i] * si[i];
      z0 += (i & 8) ? -pb : pb;
      z1 += (i & 4) ? -pb : pb;
      z2 += (i & 2) ? -pb : pb;
      z3 += (i & 1) ? -pb : pb;
    }
    int r = w * 16 + lane;
    zlds[r * 4 + 0] = z0; zlds[r * 4 + 1] = z1;
    zlds[r * 4 + 2] = z2; zlds[r * 4 + 3] = z3;
  }
  __syncthreads();

  // ---- Phase C: h = relu(q @ Wr + br) -> LDS hi/lo bf16; thread = column ----
  {
    float wr0 = Wr[tid], wr1 = Wr[256 + tid], wr2 = Wr[512 + tid], wr3 = Wr[768 + tid];
    float brv = br[tid];
    #pragma unroll 4
    for (int r = 0; r < BM; r++) {
      f32x4 z = *(const f32x4*)&zlds[r * 4];
      float hv = fmaf(z[0], wr0, fmaf(z[1], wr1, fmaf(z[2], wr2, fmaf(z[3], wr3, brv))));
      hv = fmaxf(hv, 0.f);
      unsigned short hi = f2bf(hv);
      a_hi[r * LPAD + tid] = hi;
      a_lo[r * LPAD + tid] = f2bf(hv - bf2f(hi));
    }
  }
  __syncthreads();

  const int l15 = lane & 15, l4 = lane >> 4;

  // ---- GEMM1: h2 = relu(h @ W2 + b2), accumulate in regs ----
  f32x4 acc[4][4];
  #pragma unroll
  for (int m = 0; m < 4; m++)
    #pragma unroll
    for (int n = 0; n < 4; n++) acc[m][n] = 0.f;
  gemm_tile(a_hi, a_lo, W2H, W2L, w, lane, acc);
  __syncthreads();   // all waves done READING h before overwriting with h2

  // write h2 hi/lo back into the same LDS buffers
  #pragma unroll
  for (int nf = 0; nf < 4; nf++) {
    int col = w * 64 + nf * 16 + l15;
    float b2v = b2[col];
    #pragma unroll
    for (int m = 0; m < 4; m++)
      #pragma unroll
      for (int i = 0; i < 4; i++) {
        float hv = fmaxf(acc[m][nf][i] + b2v, 0.f);
        unsigned short hi = f2bf(hv);
        int idx = (m * 16 + l4 * 4 + i) * LPAD + col;
        a_hi[idx] = hi;
        a_lo[idx] = f2bf(hv - bf2f(hi));
      }
  }
  __syncthreads();

  // ---- GEMM2: out = h2 @ W3 + b3 -> global f32 ----
  #pragma unroll
  for (int m = 0; m < 4; m++)
    #pragma unroll
    for (int n = 0; n < 4; n++) acc[m][n] = 0.f;
  gemm_tile(a_hi, a_lo, W3H, W3L, w, lane, acc);
  #pragma unroll
  for (int nf = 0; nf < 4; nf++) {
    int col = w * 64 + nf * 16 + l15;
    float b3v = b3[col];
    #pragma unroll
    for (int m = 0; m < 4; m++)
      #pragma unroll
      for (int i = 0; i < 4; i++) {
        int row = row0 + m * 16 + l4 * 4 + i;
        out[(size_t)row * 256 + col] = acc[m][nf][i] + b3v;
      }
  }
}

extern "C" void kernel_launch(void* const* d_in, const int* in_sizes, int n_in,
                              void* d_out, int out_size, void* d_ws, size_t ws_size,
                              hipStream_t stream)
{
  const float* x  = (const float*)d_in[0];
  const float* W1 = (const float*)d_in[1];
  const float* b1 = (const float*)d_in[2];
  const float* qp = (const float*)d_in[3];
  const float* Wr = (const float*)d_in[4];
  const float* br = (const float*)d_in[5];
  const float* W2 = (const float*)d_in[6];
  const float* b2 = (const float*)d_in[7];
  const float* W3 = (const float*)d_in[8];
  const float* b3 = (const float*)d_in[9];
  float* out = (float*)d_out;

  char* ws = (char*)d_ws;
  float* w1c          = (float*)ws;                       // 8 KB
  unsigned short* W2H = (unsigned short*)(ws + 8192);     // 128 KB each
  unsigned short* W2L = (unsigned short*)(ws + 8192 + 1 * 131072);
  unsigned short* W3H = (unsigned short*)(ws + 8192 + 2 * 131072);
  unsigned short* W3L = (unsigned short*)(ws + 8192 + 3 * 131072);

  prep_kernel<<<1032, 256, 0, stream>>>(W1, W2, W3, w1c, W2H, W2L, W3H, W3L);

  const int nblocks = 131072 / BM;   // 2048
  qmlp_kernel<<<nblocks, 256, 0, stream>>>(x, b1, qp, Wr, br, b2, b3,
                                           w1c, W2H, W2L, W3H, W3L, out);
}

// Round 3
// 234.261 us; speedup vs baseline: 1.5030x; 1.5030x over previous
//
#include <hip/hip_runtime.h>

typedef float  f32x4  __attribute__((ext_vector_type(4)));
typedef short  short8 __attribute__((ext_vector_type(8)));

#define BM   64
#define LPAD 264   // LDS row stride in bf16 elems (256 + 8 pad)

__device__ __forceinline__ unsigned short f2bf(float f){
  union { float f; unsigned int u; } v; v.f = f;
  unsigned int u = v.u;
  return (unsigned short)((u + 0x7FFFu + ((u >> 16) & 1u)) >> 16);
}
__device__ __forceinline__ float bf2f(unsigned short h){
  union { unsigned int u; float f; } v; v.u = ((unsigned int)h) << 16;
  return v.f;
}

// ---------------- prep: w1c = W1[:, :4]; W2 hi frag; W3 hi/lo frag ----------------
// Fragment layout: flat idx f = ((n16*8 + ks)*64 + lane)*8 + j  holds
//   bf16( W[k][n] ) with k = ks*32 + (lane>>4)*8 + j, n = n16*16 + (lane&15)
__global__ __launch_bounds__(256) void prep_kernel(
    const float* __restrict__ W1, const float* __restrict__ W2,
    const float* __restrict__ W3, float* __restrict__ w1c,
    unsigned short* __restrict__ W2H,
    unsigned short* __restrict__ W3H, unsigned short* __restrict__ W3L)
{
  int t = blockIdx.x * 256 + threadIdx.x;
  if (t < 2048) {
    w1c[t] = W1[(t >> 2) * 256 + (t & 3)];
  } else if (t < 2048 + 65536) {
    int f = t - 2048;
    int j = f & 7, lane = (f >> 3) & 63, ks = (f >> 9) & 7, n16 = f >> 12;
    int k = ks * 32 + (lane >> 4) * 8 + j;
    int n = n16 * 16 + (lane & 15);
    W2H[f] = f2bf(W2[k * 256 + n]);
  } else if (t < 2048 + 2 * 65536) {
    int f = t - 2048 - 65536;
    int j = f & 7, lane = (f >> 3) & 63, ks = (f >> 9) & 7, n16 = f >> 12;
    int k = ks * 32 + (lane >> 4) * 8 + j;
    int n = n16 * 16 + (lane & 15);
    float wv = W3[k * 256 + n];
    unsigned short hi = f2bf(wv);
    W3H[f] = hi;
    W3L[f] = f2bf(wv - bf2f(hi));
  }
}

// ---------------- kernel 1: angles + 4-qubit sim, row per thread ----------------
__global__ __launch_bounds__(256) void angle_kernel(
    const float* __restrict__ x, const float* __restrict__ b1,
    const float* __restrict__ qp, const float* __restrict__ w1c,
    float* __restrict__ z)
{
  const int row = blockIdx.x * 256 + threadIdx.x;
  const f32x4* xr = (const f32x4*)(x + (size_t)row * 512);
  const f32x4* w1 = (const f32x4*)w1c;   // w1[k] = W1[k][0..3]
  f32x4 p = {0.f, 0.f, 0.f, 0.f};
  #pragma unroll 8
  for (int i = 0; i < 128; i++) {
    f32x4 xa = xr[i];
    p += xa[0] * w1[4 * i + 0];
    p += xa[1] * w1[4 * i + 1];
    p += xa[2] * w1[4 * i + 2];
    p += xa[3] * w1[4 * i + 3];
  }
  float a0 = fmaxf(p[0] + b1[0], 0.f);
  float a1 = fmaxf(p[1] + b1[1], 0.f);
  float a2 = fmaxf(p[2] + b1[2], 0.f);
  float a3 = fmaxf(p[3] + b1[3], 0.f);

  // ---- 4-qubit statevector sim (all lanes) ----
  float g00r[4], g00i[4], g01r[4], g01i[4], g10r[4], g10i[4], g11r[4], g11i[4];
  #pragma unroll
  for (int q = 0; q < 4; q++) {
    float phi = qp[q * 3 + 0], th = qp[q * 3 + 1], om = qp[q * 3 + 2];
    float c = cosf(0.5f * th), s = sinf(0.5f * th);
    float A1 = 0.5f * (phi + om), A2 = 0.5f * (phi - om);
    float c1 = cosf(A1), s1 = sinf(A1), c2 = cosf(A2), s2 = sinf(A2);
    g00r[q] =  c * c1;  g00i[q] = -c * s1;
    g01r[q] = -s * c2;  g01i[q] = -s * s2;
    g10r[q] =  s * c2;  g10i[q] = -s * s2;
    g11r[q] =  c * c1;  g11i[q] =  c * s1;
  }
  float cr0 = cosf(0.5f * a0), sv0 = sinf(0.5f * a0);
  float cr1 = cosf(0.5f * a1), sv1 = sinf(0.5f * a1);
  float cr2 = cosf(0.5f * a2), sv2 = sinf(0.5f * a2);
  float cr3 = cosf(0.5f * a3), sv3 = sinf(0.5f * a3);
  float sr[16], si[16];
  #pragma unroll
  for (int i = 0; i < 16; i++) {
    float v = ((i & 8) ? sv0 : cr0) * ((i & 4) ? sv1 : cr1) *
              ((i & 2) ? sv2 : cr2) * ((i & 1) ? sv3 : cr3);
    sr[i] = v; si[i] = 0.f;
  }
  #pragma unroll
  for (int q = 0; q < 4; q++) {
    const int st = 8 >> q;
    #pragma unroll
    for (int i = 0; i < 16; i++) {
      if (i & st) continue;
      const int i1 = i + st;
      float xr_ = sr[i], xi_ = si[i], yr_ = sr[i1], yi_ = si[i1];
      sr[i]  = g00r[q] * xr_ - g00i[q] * xi_ + g01r[q] * yr_ - g01i[q] * yi_;
      si[i]  = g00r[q] * xi_ + g00i[q] * xr_ + g01r[q] * yi_ + g01i[q] * yr_;
      sr[i1] = g10r[q] * xr_ - g10i[q] * xi_ + g11r[q] * yr_ - g11i[q] * yi_;
      si[i1] = g10r[q] * xi_ + g10i[q] * xr_ + g11r[q] * yi_ + g11i[q] * yr_;
    }
  }
  #pragma unroll
  for (int q = 0; q < 3; q++) {
    const int cb = 8 >> q, tb = 4 >> q;
    #pragma unroll
    for (int i = 0; i < 16; i++) {
      if ((i & cb) && !(i & tb)) {
        const int j = i | tb;
        float t1 = sr[i]; sr[i] = sr[j]; sr[j] = t1;
        float t2 = si[i]; si[i] = si[j]; si[j] = t2;
      }
    }
  }
  float z0 = 0.f, z1 = 0.f, z2 = 0.f, z3 = 0.f;
  #pragma unroll
  for (int i = 0; i < 16; i++) {
    float pb = sr[i] * sr[i] + si[i] * si[i];
    z0 += (i & 8) ? -pb : pb;
    z1 += (i & 4) ? -pb : pb;
    z2 += (i & 2) ? -pb : pb;
    z3 += (i & 1) ? -pb : pb;
  }
  f32x4 zv = {z0, z1, z2, z3};
  ((f32x4*)z)[row] = zv;
}

// ---------------- kernel 2: h = relu(z@Wr+br); GEMM1 (2-term); GEMM2 (3-term) ----
__global__ __launch_bounds__(256) void mlp_kernel(
    const float* __restrict__ z,  const float* __restrict__ Wr,
    const float* __restrict__ br, const float* __restrict__ b2,
    const float* __restrict__ b3,
    const unsigned short* __restrict__ W2H,
    const unsigned short* __restrict__ W3H, const unsigned short* __restrict__ W3L,
    float* __restrict__ out)
{
  __shared__ f32x4 zl[BM];
  __shared__ unsigned short a_hi[BM * LPAD];
  __shared__ unsigned short a_lo[BM * LPAD];

  const int tid = threadIdx.x;
  const int w = tid >> 6, lane = tid & 63;
  const int l15 = lane & 15, l4 = lane >> 4;
  const int row0 = blockIdx.x * BM;

  if (tid < BM) zl[tid] = ((const f32x4*)z)[row0 + tid];
  __syncthreads();

  // Phase C: h = relu(z @ Wr + br) -> hi/lo bf16 LDS; thread = column
  {
    float wr0 = Wr[tid], wr1 = Wr[256 + tid], wr2 = Wr[512 + tid], wr3 = Wr[768 + tid];
    float brv = br[tid];
    #pragma unroll 4
    for (int r = 0; r < BM; r++) {
      f32x4 zz = zl[r];
      float hv = fmaf(zz[0], wr0, fmaf(zz[1], wr1, fmaf(zz[2], wr2, fmaf(zz[3], wr3, brv))));
      hv = fmaxf(hv, 0.f);
      unsigned short hi = f2bf(hv);
      a_hi[r * LPAD + tid] = hi;
      a_lo[r * LPAD + tid] = f2bf(hv - bf2f(hi));
    }
  }
  __syncthreads();

  // GEMM1: h2 = relu(h @ W2 + b2); 2-term (A hi/lo x B hi)
  f32x4 acc[4][4];
  #pragma unroll
  for (int m = 0; m < 4; m++)
    #pragma unroll
    for (int n = 0; n < 4; n++) acc[m][n] = 0.f;
  #pragma unroll
  for (int ks = 0; ks < 8; ks++) {
    short8 ah[4], al[4];
    #pragma unroll
    for (int m = 0; m < 4; m++) {
      ah[m] = *(const short8*)&a_hi[(m * 16 + l15) * LPAD + ks * 32 + l4 * 8];
      al[m] = *(const short8*)&a_lo[(m * 16 + l15) * LPAD + ks * 32 + l4 * 8];
    }
    #pragma unroll
    for (int nf = 0; nf < 4; nf++) {
      short8 bh = *(const short8*)&W2H[(size_t)(((w * 4 + nf) * 8 + ks) * 64 + lane) * 8];
      #pragma unroll
      for (int m = 0; m < 4; m++) {
        acc[m][nf] = __builtin_amdgcn_mfma_f32_16x16x32_bf16(ah[m], bh, acc[m][nf], 0, 0, 0);
        acc[m][nf] = __builtin_amdgcn_mfma_f32_16x16x32_bf16(al[m], bh, acc[m][nf], 0, 0, 0);
      }
    }
  }
  __syncthreads();   // all waves done reading h

  // write h2 hi/lo into the same LDS buffers
  #pragma unroll
  for (int nf = 0; nf < 4; nf++) {
    int col = w * 64 + nf * 16 + l15;
    float b2v = b2[col];
    #pragma unroll
    for (int m = 0; m < 4; m++)
      #pragma unroll
      for (int i = 0; i < 4; i++) {
        float hv = fmaxf(acc[m][nf][i] + b2v, 0.f);
        unsigned short hi = f2bf(hv);
        int idx = (m * 16 + l4 * 4 + i) * LPAD + col;
        a_hi[idx] = hi;
        a_lo[idx] = f2bf(hv - bf2f(hi));
      }
  }
  __syncthreads();

  // GEMM2: out = h2 @ W3 + b3; 3-term
  #pragma unroll
  for (int m = 0; m < 4; m++)
    #pragma unroll
    for (int n = 0; n < 4; n++) acc[m][n] = 0.f;
  #pragma unroll
  for (int ks = 0; ks < 8; ks++) {
    short8 ah[4], al[4];
    #pragma unroll
    for (int m = 0; m < 4; m++) {
      ah[m] = *(const short8*)&a_hi[(m * 16 + l15) * LPAD + ks * 32 + l4 * 8];
      al[m] = *(const short8*)&a_lo[(m * 16 + l15) * LPAD + ks * 32 + l4 * 8];
    }
    #pragma unroll
    for (int nf = 0; nf < 4; nf++) {
      size_t boff = (size_t)(((w * 4 + nf) * 8 + ks) * 64 + lane) * 8;
      short8 bh = *(const short8*)&W3H[boff];
      short8 bl = *(const short8*)&W3L[boff];
      #pragma unroll
      for (int m = 0; m < 4; m++) {
        acc[m][nf] = __builtin_amdgcn_mfma_f32_16x16x32_bf16(ah[m], bh, acc[m][nf], 0, 0, 0);
        acc[m][nf] = __builtin_amdgcn_mfma_f32_16x16x32_bf16(al[m], bh, acc[m][nf], 0, 0, 0);
        acc[m][nf] = __builtin_amdgcn_mfma_f32_16x16x32_bf16(ah[m], bl, acc[m][nf], 0, 0, 0);
      }
    }
  }
  #pragma unroll
  for (int nf = 0; nf < 4; nf++) {
    int col = w * 64 + nf * 16 + l15;
    float b3v = b3[col];
    #pragma unroll
    for (int m = 0; m < 4; m++)
      #pragma unroll
      for (int i = 0; i < 4; i++) {
        int row = row0 + m * 16 + l4 * 4 + i;
        out[(size_t)row * 256 + col] = acc[m][nf][i] + b3v;
      }
  }
}

extern "C" void kernel_launch(void* const* d_in, const int* in_sizes, int n_in,
                              void* d_out, int out_size, void* d_ws, size_t ws_size,
                              hipStream_t stream)
{
  const float* x  = (const float*)d_in[0];
  const float* W1 = (const float*)d_in[1];
  const float* b1 = (const float*)d_in[2];
  const float* qp = (const float*)d_in[3];
  const float* Wr = (const float*)d_in[4];
  const float* br = (const float*)d_in[5];
  const float* W2 = (const float*)d_in[6];
  const float* b2 = (const float*)d_in[7];
  const float* W3 = (const float*)d_in[8];
  const float* b3 = (const float*)d_in[9];
  float* out = (float*)d_out;

  char* ws = (char*)d_ws;
  float* w1c          = (float*)ws;                                   // 8 KB
  unsigned short* W2H = (unsigned short*)(ws + 8192);                 // 128 KB
  unsigned short* W3H = (unsigned short*)(ws + 8192 + 1 * 131072);    // 128 KB
  unsigned short* W3L = (unsigned short*)(ws + 8192 + 2 * 131072);    // 128 KB
  float* z            = (float*)(ws + 8192 + 3 * 131072);             // 2 MB

  prep_kernel<<<520, 256, 0, stream>>>(W1, W2, W3, w1c, W2H, W3H, W3L);
  angle_kernel<<<512, 256, 0, stream>>>(x, b1, qp, w1c, z);
  mlp_kernel<<<2048, 256, 0, stream>>>(z, Wr, br, b2, b3, W2H, W3H, W3L, out);
}

// Round 4
// 166.782 us; speedup vs baseline: 2.1110x; 1.4046x over previous
//
#include <hip/hip_runtime.h>

typedef float  f32x4  __attribute__((ext_vector_type(4)));
typedef short  short8 __attribute__((ext_vector_type(8)));

#define BM   32
#define LPAD 264   // LDS row stride in bf16 elems (256 + 8 pad)

__device__ __forceinline__ unsigned short f2bf(float f){
  union { float f; unsigned int u; } v; v.f = f;
  unsigned int u = v.u;
  return (unsigned short)((u + 0x7FFFu + ((u >> 16) & 1u)) >> 16);
}
__device__ __forceinline__ float bf2f(unsigned short h){
  union { unsigned int u; float f; } v; v.u = ((unsigned int)h) << 16;
  return v.f;
}

// ---------------- prep: w1c = W1[:, :4]; W2 hi frag; W3 hi/lo frag ----------------
// Fragment layout: flat idx f = ((n16*8 + ks)*64 + lane)*8 + j  holds
//   bf16( W[k][n] ) with k = ks*32 + (lane>>4)*8 + j, n = n16*16 + (lane&15)
__global__ __launch_bounds__(256) void prep_kernel(
    const float* __restrict__ W1, const float* __restrict__ W2,
    const float* __restrict__ W3, float* __restrict__ w1c,
    unsigned short* __restrict__ W2H,
    unsigned short* __restrict__ W3H, unsigned short* __restrict__ W3L)
{
  int t = blockIdx.x * 256 + threadIdx.x;
  if (t < 2048) {
    w1c[t] = W1[(t >> 2) * 256 + (t & 3)];
  } else if (t < 2048 + 65536) {
    int f = t - 2048;
    int j = f & 7, lane = (f >> 3) & 63, ks = (f >> 9) & 7, n16 = f >> 12;
    int k = ks * 32 + (lane >> 4) * 8 + j;
    int n = n16 * 16 + (lane & 15);
    W2H[f] = f2bf(W2[k * 256 + n]);
  } else if (t < 2048 + 2 * 65536) {
    int f = t - 2048 - 65536;
    int j = f & 7, lane = (f >> 3) & 63, ks = (f >> 9) & 7, n16 = f >> 12;
    int k = ks * 32 + (lane >> 4) * 8 + j;
    int n = n16 * 16 + (lane & 15);
    float wv = W3[k * 256 + n];
    unsigned short hi = f2bf(wv);
    W3H[f] = hi;
    W3L[f] = f2bf(wv - bf2f(hi));
  }
}

// ---------------- kernel 1: angles + 4-qubit sim, row per thread ----------------
__global__ __launch_bounds__(256) void angle_kernel(
    const float* __restrict__ x, const float* __restrict__ b1,
    const float* __restrict__ qp, const float* __restrict__ w1c,
    float* __restrict__ z)
{
  const int row = blockIdx.x * 256 + threadIdx.x;
  const f32x4* xr = (const f32x4*)(x + (size_t)row * 512);
  const f32x4* w1 = (const f32x4*)w1c;   // w1[k] = W1[k][0..3]
  f32x4 p = {0.f, 0.f, 0.f, 0.f};
  #pragma unroll 8
  for (int i = 0; i < 128; i++) {
    f32x4 xa = xr[i];
    p += xa[0] * w1[4 * i + 0];
    p += xa[1] * w1[4 * i + 1];
    p += xa[2] * w1[4 * i + 2];
    p += xa[3] * w1[4 * i + 3];
  }
  float a0 = fmaxf(p[0] + b1[0], 0.f);
  float a1 = fmaxf(p[1] + b1[1], 0.f);
  float a2 = fmaxf(p[2] + b1[2], 0.f);
  float a3 = fmaxf(p[3] + b1[3], 0.f);

  // ---- 4-qubit statevector sim (all lanes) ----
  float g00r[4], g00i[4], g01r[4], g01i[4], g10r[4], g10i[4], g11r[4], g11i[4];
  #pragma unroll
  for (int q = 0; q < 4; q++) {
    float phi = qp[q * 3 + 0], th = qp[q * 3 + 1], om = qp[q * 3 + 2];
    float c = cosf(0.5f * th), s = sinf(0.5f * th);
    float A1 = 0.5f * (phi + om), A2 = 0.5f * (phi - om);
    float c1 = cosf(A1), s1 = sinf(A1), c2 = cosf(A2), s2 = sinf(A2);
    g00r[q] =  c * c1;  g00i[q] = -c * s1;
    g01r[q] = -s * c2;  g01i[q] = -s * s2;
    g10r[q] =  s * c2;  g10i[q] = -s * s2;
    g11r[q] =  c * c1;  g11i[q] =  c * s1;
  }
  float cr0 = cosf(0.5f * a0), sv0 = sinf(0.5f * a0);
  float cr1 = cosf(0.5f * a1), sv1 = sinf(0.5f * a1);
  float cr2 = cosf(0.5f * a2), sv2 = sinf(0.5f * a2);
  float cr3 = cosf(0.5f * a3), sv3 = sinf(0.5f * a3);
  float sr[16], si[16];
  #pragma unroll
  for (int i = 0; i < 16; i++) {
    float v = ((i & 8) ? sv0 : cr0) * ((i & 4) ? sv1 : cr1) *
              ((i & 2) ? sv2 : cr2) * ((i & 1) ? sv3 : cr3);
    sr[i] = v; si[i] = 0.f;
  }
  #pragma unroll
  for (int q = 0; q < 4; q++) {
    const int st = 8 >> q;
    #pragma unroll
    for (int i = 0; i < 16; i++) {
      if (i & st) continue;
      const int i1 = i + st;
      float xr_ = sr[i], xi_ = si[i], yr_ = sr[i1], yi_ = si[i1];
      sr[i]  = g00r[q] * xr_ - g00i[q] * xi_ + g01r[q] * yr_ - g01i[q] * yi_;
      si[i]  = g00r[q] * xi_ + g00i[q] * xr_ + g01r[q] * yi_ + g01i[q] * yr_;
      sr[i1] = g10r[q] * xr_ - g10i[q] * xi_ + g11r[q] * yr_ - g11i[q] * yi_;
      si[i1] = g10r[q] * xi_ + g10i[q] * xr_ + g11r[q] * yi_ + g11i[q] * yr_;
    }
  }
  #pragma unroll
  for (int q = 0; q < 3; q++) {
    const int cb = 8 >> q, tb = 4 >> q;
    #pragma unroll
    for (int i = 0; i < 16; i++) {
      if ((i & cb) && !(i & tb)) {
        const int j = i | tb;
        float t1 = sr[i]; sr[i] = sr[j]; sr[j] = t1;
        float t2 = si[i]; si[i] = si[j]; si[j] = t2;
      }
    }
  }
  float z0 = 0.f, z1 = 0.f, z2 = 0.f, z3 = 0.f;
  #pragma unroll
  for (int i = 0; i < 16; i++) {
    float pb = sr[i] * sr[i] + si[i] * si[i];
    z0 += (i & 8) ? -pb : pb;
    z1 += (i & 4) ? -pb : pb;
    z2 += (i & 2) ? -pb : pb;
    z3 += (i & 1) ? -pb : pb;
  }
  f32x4 zv = {z0, z1, z2, z3};
  ((f32x4*)z)[row] = zv;
}

// ---------------- kernel 2: h = relu(z@Wr+br); GEMM1 (2-term); GEMM2 (3-term) ----
// LDS: [0,512) zl | [512, 512+16896) a_hi | [+16896) a_lo ; f32 stage aliases a_hi/a_lo
__global__ __launch_bounds__(256, 4) void mlp_kernel(
    const float* __restrict__ z,  const float* __restrict__ Wr,
    const float* __restrict__ br, const float* __restrict__ b2,
    const float* __restrict__ b3,
    const unsigned short* __restrict__ W2H,
    const unsigned short* __restrict__ W3H, const unsigned short* __restrict__ W3L,
    float* __restrict__ out)
{
  __shared__ __align__(16) char smem[512 + 2 * BM * LPAD * 2];
  f32x4* zl = (f32x4*)smem;
  unsigned short* a_hi = (unsigned short*)(smem + 512);
  unsigned short* a_lo = (unsigned short*)(smem + 512 + BM * LPAD * 2);
  float* fstage = (float*)(smem + 512);              // [32][260] f32 = 33280 B

  const int tid = threadIdx.x;
  const int w = tid >> 6, lane = tid & 63;
  const int l15 = lane & 15, l4 = lane >> 4;
  const int row0 = blockIdx.x * BM;

  if (tid < BM) zl[tid] = ((const f32x4*)z)[row0 + tid];
  __syncthreads();

  // Phase C: h = relu(z @ Wr + br) -> hi/lo bf16 LDS; thread = column
  {
    float wr0 = Wr[tid], wr1 = Wr[256 + tid], wr2 = Wr[512 + tid], wr3 = Wr[768 + tid];
    float brv = br[tid];
    #pragma unroll 4
    for (int r = 0; r < BM; r++) {
      f32x4 zz = zl[r];
      float hv = fmaf(zz[0], wr0, fmaf(zz[1], wr1, fmaf(zz[2], wr2, fmaf(zz[3], wr3, brv))));
      hv = fmaxf(hv, 0.f);
      unsigned short hi = f2bf(hv);
      a_hi[r * LPAD + tid] = hi;
      a_lo[r * LPAD + tid] = f2bf(hv - bf2f(hi));
    }
  }
  __syncthreads();

  // GEMM1: h2 = relu(h @ W2 + b2); 2-term (A hi/lo x B hi)
  f32x4 acc[2][4];
  #pragma unroll
  for (int m = 0; m < 2; m++)
    #pragma unroll
    for (int n = 0; n < 4; n++) acc[m][n] = 0.f;
  #pragma unroll
  for (int ks = 0; ks < 8; ks++) {
    short8 ah[2], al[2];
    #pragma unroll
    for (int m = 0; m < 2; m++) {
      ah[m] = *(const short8*)&a_hi[(m * 16 + l15) * LPAD + ks * 32 + l4 * 8];
      al[m] = *(const short8*)&a_lo[(m * 16 + l15) * LPAD + ks * 32 + l4 * 8];
    }
    #pragma unroll
    for (int nf = 0; nf < 4; nf++) {
      short8 bh = *(const short8*)&W2H[(size_t)(((w * 4 + nf) * 8 + ks) * 64 + lane) * 8];
      #pragma unroll
      for (int m = 0; m < 2; m++) {
        acc[m][nf] = __builtin_amdgcn_mfma_f32_16x16x32_bf16(ah[m], bh, acc[m][nf], 0, 0, 0);
        acc[m][nf] = __builtin_amdgcn_mfma_f32_16x16x32_bf16(al[m], bh, acc[m][nf], 0, 0, 0);
      }
    }
  }
  __syncthreads();   // all waves done reading h

  // write h2 hi/lo into the same LDS buffers
  #pragma unroll
  for (int nf = 0; nf < 4; nf++) {
    int col = w * 64 + nf * 16 + l15;
    float b2v = b2[col];
    #pragma unroll
    for (int m = 0; m < 2; m++)
      #pragma unroll
      for (int i = 0; i < 4; i++) {
        float hv = fmaxf(acc[m][nf][i] + b2v, 0.f);
        unsigned short hi = f2bf(hv);
        int idx = (m * 16 + l4 * 4 + i) * LPAD + col;
        a_hi[idx] = hi;
        a_lo[idx] = f2bf(hv - bf2f(hi));
      }
  }
  __syncthreads();

  // GEMM2: out = h2 @ W3 + b3; 3-term
  #pragma unroll
  for (int m = 0; m < 2; m++)
    #pragma unroll
    for (int n = 0; n < 4; n++) acc[m][n] = 0.f;
  #pragma unroll
  for (int ks = 0; ks < 8; ks++) {
    short8 ah[2], al[2];
    #pragma unroll
    for (int m = 0; m < 2; m++) {
      ah[m] = *(const short8*)&a_hi[(m * 16 + l15) * LPAD + ks * 32 + l4 * 8];
      al[m] = *(const short8*)&a_lo[(m * 16 + l15) * LPAD + ks * 32 + l4 * 8];
    }
    #pragma unroll
    for (int nf = 0; nf < 4; nf++) {
      size_t boff = (size_t)(((w * 4 + nf) * 8 + ks) * 64 + lane) * 8;
      short8 bh = *(const short8*)&W3H[boff];
      short8 bl = *(const short8*)&W3L[boff];
      #pragma unroll
      for (int m = 0; m < 2; m++) {
        acc[m][nf] = __builtin_amdgcn_mfma_f32_16x16x32_bf16(ah[m], bh, acc[m][nf], 0, 0, 0);
        acc[m][nf] = __builtin_amdgcn_mfma_f32_16x16x32_bf16(al[m], bh, acc[m][nf], 0, 0, 0);
        acc[m][nf] = __builtin_amdgcn_mfma_f32_16x16x32_bf16(ah[m], bl, acc[m][nf], 0, 0, 0);
      }
    }
  }
  __syncthreads();   // all waves done reading h2 before f32 stage overwrites LDS

  // stage f32 tile in LDS, then fully-coalesced 1KB-row stores
  #pragma unroll
  for (int nf = 0; nf < 4; nf++) {
    int col = w * 64 + nf * 16 + l15;
    float b3v = b3[col];
    #pragma unroll
    for (int m = 0; m < 2; m++)
      #pragma unroll
      for (int i = 0; i < 4; i++)
        fstage[(m * 16 + l4 * 4 + i) * 260 + col] = acc[m][nf][i] + b3v;
  }
  __syncthreads();
  #pragma unroll
  for (int rr = 0; rr < 8; rr++) {
    int row = w * 8 + rr;
    f32x4 v = ((const f32x4*)&fstage[row * 260])[lane];
    ((f32x4*)(out + (size_t)(row0 + row) * 256))[lane] = v;
  }
}

extern "C" void kernel_launch(void* const* d_in, const int* in_sizes, int n_in,
                              void* d_out, int out_size, void* d_ws, size_t ws_size,
                              hipStream_t stream)
{
  const float* x  = (const float*)d_in[0];
  const float* W1 = (const float*)d_in[1];
  const float* b1 = (const float*)d_in[2];
  const float* qp = (const float*)d_in[3];
  const float* Wr = (const float*)d_in[4];
  const float* br = (const float*)d_in[5];
  const float* W2 = (const float*)d_in[6];
  const float* b2 = (const float*)d_in[7];
  const float* W3 = (const float*)d_in[8];
  const float* b3 = (const float*)d_in[9];
  float* out = (float*)d_out;

  char* ws = (char*)d_ws;
  float* w1c          = (float*)ws;                                   // 8 KB
  unsigned short* W2H = (unsigned short*)(ws + 8192);                 // 128 KB
  unsigned short* W3H = (unsigned short*)(ws + 8192 + 1 * 131072);    // 128 KB
  unsigned short* W3L = (unsigned short*)(ws + 8192 + 2 * 131072);    // 128 KB
  float* z            = (float*)(ws + 8192 + 3 * 131072);             // 2 MB

  prep_kernel<<<520, 256, 0, stream>>>(W1, W2, W3, w1c, W2H, W3H, W3L);
  angle_kernel<<<512, 256, 0, stream>>>(x, b1, qp, w1c, z);
  mlp_kernel<<<4096, 256, 0, stream>>>(z, Wr, br, b2, b3, W2H, W3H, W3L, out);
}